// Round 9
// baseline (219.661 us; speedup 1.0000x reference)
//
#include <hip/hip_runtime.h>
#include <hip/hip_bf16.h>

#define D_MODEL 256
#define NHEADS 4
#define DHEAD 64
#define BATCH 4
#define TSEQ 2048
#define CHUNK 64
#define NCHUNK (TSEQ / CHUNK)   // 32
#define NTOK (BATCH * TSEQ)     // 8192
#define NBH (BATCH * NHEADS)    // 16
#define EPSV 1e-6f
#define LSTRF 68                // fp32 LDS row stride (verified)

typedef __bf16 bf16x8 __attribute__((ext_vector_type(8)));
typedef float f32x4 __attribute__((ext_vector_type(4)));
typedef unsigned short us8 __attribute__((ext_vector_type(8)));

__device__ __forceinline__ float elu1(float a) {
    return a > 0.0f ? a + 1.0f : __expf(a);
}

__device__ __forceinline__ unsigned short f2bf(float f) {
    __hip_bfloat16 h = __float2bfloat16(f);   // RNE
    return __builtin_bit_cast(unsigned short, h);
}

__device__ __forceinline__ float bf2f(unsigned short u) {
    return __bfloat162float(__builtin_bit_cast(__hip_bfloat16, u));
}

// Build a bf16x8 MFMA fragment from 8 consecutive fp32 values (16B-aligned).
// Verified class (R7): 2x float4 LDS reads + VALU cvt.
__device__ __forceinline__ bf16x8 frag8(const float* p) {
    const float4 x = *reinterpret_cast<const float4*>(p);
    const float4 y = *reinterpret_cast<const float4*>(p + 4);
    us8 u;
    u[0] = f2bf(x.x); u[1] = f2bf(x.y); u[2] = f2bf(x.z); u[3] = f2bf(x.w);
    u[4] = f2bf(y.x); u[5] = f2bf(y.y); u[6] = f2bf(y.z); u[7] = f2bf(y.w);
    return __builtin_bit_cast(bf16x8, u);
}

// async global->LDS, 16B per lane; lds ptr must be wave-uniform base.
__device__ __forceinline__ void gld_lds16(const void* g, void* l) {
    __builtin_amdgcn_global_load_lds(
        (const __attribute__((address_space(1))) void*)g,
        (__attribute__((address_space(3))) void*)l, 16, 0, 0);
}

// ---------------------------------------------------------------------------
// fused converts: blocks [0,1024): x->bf16; blocks [1024,1088): W transposes
// (exactly R7's two verified kernels glued by block range)
// ---------------------------------------------------------------------------
__global__ __launch_bounds__(256) void convert_kernel(
    const float* __restrict__ x,
    const float* __restrict__ Wq, const float* __restrict__ Wk,
    const float* __restrict__ Wv, const float* __restrict__ Wo,
    unsigned short* __restrict__ xb,
    unsigned short* __restrict__ Wt, unsigned short* __restrict__ Wot)
{
    const int tid = threadIdx.x;
    if (blockIdx.x < NTOK * D_MODEL / 8 / 256) {
        const int i = (blockIdx.x * 256 + tid) * 8;
        const float4 a = *reinterpret_cast<const float4*>(&x[i]);
        const float4 b = *reinterpret_cast<const float4*>(&x[i + 4]);
        ushort4 u0 = { f2bf(a.x), f2bf(a.y), f2bf(a.z), f2bf(a.w) };
        ushort4 u1 = { f2bf(b.x), f2bf(b.y), f2bf(b.z), f2bf(b.w) };
        *reinterpret_cast<ushort4*>(&xb[i]) = u0;
        *reinterpret_cast<ushort4*>(&xb[i + 4]) = u1;
        return;
    }
    __shared__ float Ls[64][65];
    const int bid = blockIdx.x - NTOK * D_MODEL / 8 / 256;
    const int wi = bid >> 4;
    const int ti = bid & 15;
    const int k0 = (ti >> 2) * 64, n0 = (ti & 3) * 64;
    const float* W = wi == 0 ? Wq : wi == 1 ? Wk : wi == 2 ? Wv : Wo;
#pragma unroll
    for (int i = 0; i < 16; ++i) {
        const int idx = i * 256 + tid;
        const int r = idx >> 6, c = idx & 63;
        Ls[r][c] = W[(size_t)(k0 + r) * D_MODEL + n0 + c];
    }
    __syncthreads();
    unsigned short* outp = (wi < 3) ? (Wt + (size_t)(wi * 256 + n0) * D_MODEL + k0)
                                    : (Wot + (size_t)n0 * D_MODEL + k0);
#pragma unroll
    for (int i = 0; i < 16; ++i) {
        const int idx = i * 256 + tid;
        const int rn = idx >> 6, ck = idx & 63;
        outp[(size_t)rn * D_MODEL + ck] = f2bf(Ls[ck][rn]);
    }
}

// ---------------------------------------------------------------------------
// MFMA bf16 GEMM, m97 structure (verified): 128x128 tile, BK=64,
// global_load_lds(16B), chunk-XOR LDS swizzle.
// MODE 0: qkv -> bf16 Q/K/V with elu1 on Q,K.  MODE 1: -> fp32 out.
// ---------------------------------------------------------------------------
template<int MODE>
__global__ __launch_bounds__(256) void mfma_gemm_kernel(
    const unsigned short* __restrict__ A,
    const unsigned short* __restrict__ Bt,
    const float* __restrict__ b0, const float* __restrict__ b1,
    const float* __restrict__ b2,
    void* __restrict__ O0, void* __restrict__ O1, void* __restrict__ O2)
{
    __shared__ __align__(16) unsigned short As[128 * 64];
    __shared__ __align__(16) unsigned short Bs[128 * 64];
    const int tid = threadIdx.x;
    const int wave = tid >> 6, lane = tid & 63;
    const int la = lane & 15, q = lane >> 4;
    const int wm = (wave >> 1) * 64, wn = (wave & 1) * 64;

    int mtile, ntile;
    if (MODE == 0) { ntile = blockIdx.x % 6; mtile = blockIdx.x / 6; }
    else           { ntile = blockIdx.x & 1; mtile = blockIdx.x >> 1; }
    const int m0 = mtile * 128, n0 = ntile * 128;

    const unsigned short* Ab = A  + (size_t)m0 * D_MODEL;
    const unsigned short* Bb = Bt + (size_t)n0 * D_MODEL;

    f32x4 acc[4][4];
#pragma unroll
    for (int i = 0; i < 4; ++i)
#pragma unroll
        for (int j = 0; j < 4; ++j) acc[i][j] = (f32x4){0.f, 0.f, 0.f, 0.f};

    for (int k0 = 0; k0 < D_MODEL; k0 += 64) {
#pragma unroll
        for (int i = 0; i < 4; ++i) {
            const int bslot = i * 256 + wave * 64;
            const int slot = bslot + lane;
            const int m = slot >> 3, s = slot & 7;
            const int g = s ^ (m & 7);
            gld_lds16(Ab + (size_t)m * D_MODEL + k0 + g * 8, &As[bslot * 8]);
            gld_lds16(Bb + (size_t)m * D_MODEL + k0 + g * 8, &Bs[bslot * 8]);
        }
        __syncthreads();

        bf16x8 af[4][2], bfr[4][2];
#pragma unroll
        for (int i = 0; i < 4; ++i) {
#pragma unroll
            for (int kh = 0; kh < 2; ++kh) {
                const int g = kh * 4 + q;
                const int m = wm + i * 16 + la;
                af[i][kh] = *reinterpret_cast<const bf16x8*>(
                    &As[m * 64 + ((g ^ (m & 7)) << 3)]);
                const int n = wn + i * 16 + la;
                bfr[i][kh] = *reinterpret_cast<const bf16x8*>(
                    &Bs[n * 64 + ((g ^ (n & 7)) << 3)]);
            }
        }
#pragma unroll
        for (int mi = 0; mi < 4; ++mi)
#pragma unroll
            for (int ni = 0; ni < 4; ++ni) {
                acc[mi][ni] = __builtin_amdgcn_mfma_f32_16x16x32_bf16(
                    af[mi][0], bfr[ni][0], acc[mi][ni], 0, 0, 0);
                acc[mi][ni] = __builtin_amdgcn_mfma_f32_16x16x32_bf16(
                    af[mi][1], bfr[ni][1], acc[mi][ni], 0, 0, 0);
            }
        __syncthreads();
    }

    // C/D layout: col=lane&15, row=(lane>>4)*4+reg
#pragma unroll
    for (int mi = 0; mi < 4; ++mi) {
#pragma unroll
        for (int ni = 0; ni < 4; ++ni) {
            const int row = m0 + wm + mi * 16 + q * 4;
            const int col = n0 + wn + ni * 16 + la;
            if (MODE == 0) {
                const int which = col >> 8;          // block-uniform
                const int cl = col & 255;
                unsigned short* Out = (unsigned short*)
                    (which == 0 ? O0 : which == 1 ? O1 : O2);
                const float* bias = which == 0 ? b0 : which == 1 ? b1 : b2;
                const int act = (which < 2);
                const float bv = bias[cl];
#pragma unroll
                for (int r = 0; r < 4; ++r) {
                    float v = acc[mi][ni][r] + bv;
                    if (act) v = elu1(v);
                    Out[(size_t)(row + r) * D_MODEL + cl] = f2bf(v);
                }
            } else {
                float* Out = (float*)O0;
                const float bv = b0[col];
#pragma unroll
                for (int r = 0; r < 4; ++r)
                    Out[(size_t)(row + r) * D_MODEL + col] = acc[mi][ni][r] + bv;
            }
        }
    }
}

// ---------------------------------------------------------------------------
// FUSED scan: chunksum + prefix + chunkout in one kernel.
// Grid: 64 blocks = (b,h) x 4 m-slices (16 V-cols each). Each block walks its
// 32 chunks sequentially keeping running S^T[m][d] (fp32) and Z[d] in LDS.
// R9 change vs R8: ALL staging uses R7-verified scalar bf16 global loads +
// b32 LDS stores (no bf16x8 global loads); K-retranspose is LDS->LDS.
// ---------------------------------------------------------------------------
__global__ __launch_bounds__(256) void scan_kernel(
    const unsigned short* __restrict__ Qb, const unsigned short* __restrict__ Kb,
    const unsigned short* __restrict__ Vb, unsigned short* __restrict__ Ob)
{
    __shared__ float Qs[64 * LSTRF];     // Qs[t][d]
    __shared__ float Ks[64 * LSTRF];     // Ks[s][d]
    __shared__ float AtKt[64 * LSTRF];   // phase1 At[t][s]; phase2 Kt[d][t]
    __shared__ float Vt[16 * LSTRF];     // Vt[m][s]   (m-slice)
    __shared__ float St[16 * LSTRF];     // St[m][d]   running S^T, exclusive
    __shared__ float zsh[64];            // running Z, exclusive
    __shared__ float part[64 * 5];       // denom partials [t][q4]
    __shared__ float zp[64 * 5];         // z partials [d][q4]

    const int tid = threadIdx.x;
    const int wave = tid >> 6, lane = tid & 63;
    const int la = lane & 15, q = lane >> 4;
    const int td = tid & 63, q4 = tid >> 6;
    const int bh = blockIdx.x >> 2, mh = blockIdx.x & 3;
    const int b = bh >> 2, h = bh & 3;
    const size_t hbase = (size_t)b * TSEQ * D_MODEL + h * DHEAD;

    for (int i = tid; i < 16 * LSTRF; i += 256) St[i] = 0.f;
    if (tid < 64) zsh[tid] = 0.f;
    __syncthreads();

    for (int c = 0; c < NCHUNK; ++c) {
        const size_t gq = hbase + (size_t)c * CHUNK * D_MODEL;

        // (a) stage Q,K row-major (scalar loads, R7-verified class)
#pragma unroll
        for (int i = 0; i < 16; ++i) {
            const int idx = i * 256 + tid;
            const int t = idx >> 6, d = idx & 63;
            Qs[t * LSTRF + d] = bf2f(Qb[gq + (size_t)t * D_MODEL + d]);
            Ks[t * LSTRF + d] = bf2f(Kb[gq + (size_t)t * D_MODEL + d]);
        }
        // V-slice transposed: Vt[m][t], scalar loads + b32 scatter
#pragma unroll
        for (int i = 0; i < 4; ++i) {
            const int idx = i * 256 + tid;
            const int t = idx >> 4, m = idx & 15;
            Vt[m * LSTRF + t] = bf2f(Vb[gq + (size_t)t * D_MODEL + mh * 16 + m]);
        }
        __syncthreads();

        // (b) A = tril(Q K^T): 4 waves x 2x2 tiles of 16x16 over 64x64
        {
            const int wt2 = (wave >> 1) * 32, wn2 = (wave & 1) * 32;
            f32x4 acc[2][2];
#pragma unroll
            for (int i = 0; i < 2; ++i)
#pragma unroll
                for (int j = 0; j < 2; ++j) acc[i][j] = (f32x4){0.f, 0.f, 0.f, 0.f};
#pragma unroll
            for (int ks = 0; ks < 2; ++ks) {
                const int ko = ks * 32 + q * 8;
                const bf16x8 a0  = frag8(&Qs[(wt2 + la) * LSTRF + ko]);
                const bf16x8 a1  = frag8(&Qs[(wt2 + 16 + la) * LSTRF + ko]);
                const bf16x8 bb0 = frag8(&Ks[(wn2 + la) * LSTRF + ko]);
                const bf16x8 bb1 = frag8(&Ks[(wn2 + 16 + la) * LSTRF + ko]);
                acc[0][0] = __builtin_amdgcn_mfma_f32_16x16x32_bf16(a0, bb0, acc[0][0], 0, 0, 0);
                acc[0][1] = __builtin_amdgcn_mfma_f32_16x16x32_bf16(a0, bb1, acc[0][1], 0, 0, 0);
                acc[1][0] = __builtin_amdgcn_mfma_f32_16x16x32_bf16(a1, bb0, acc[1][0], 0, 0, 0);
                acc[1][1] = __builtin_amdgcn_mfma_f32_16x16x32_bf16(a1, bb1, acc[1][1], 0, 0, 0);
            }
#pragma unroll
            for (int mi = 0; mi < 2; ++mi)
#pragma unroll
                for (int ni = 0; ni < 2; ++ni) {
                    const int t0 = wt2 + mi * 16 + q * 4;
                    const int s  = wn2 + ni * 16 + la;
#pragma unroll
                    for (int r = 0; r < 4; ++r)
                        AtKt[(t0 + r) * LSTRF + s] =
                            (s <= t0 + r) ? acc[mi][ni][r] : 0.f;
                }
        }
        // z partials: thread (d=td, q4): sum of Ks[t][d] over its t-range
        {
            float zv = 0.f;
            for (int t = q4 * 16; t < q4 * 16 + 16; ++t) zv += Ks[t * LSTRF + td];
            zp[td * 5 + q4] = zv;
        }
        __syncthreads();

        // (c) denom partials: thread (t=td, q4)
        {
            float pv = 0.f;
            for (int s = q4 * 16; s < q4 * 16 + 16; ++s) pv += AtKt[td * LSTRF + s];
            for (int d = q4 * 16; d < q4 * 16 + 16; ++d)
                pv = fmaf(Qs[td * LSTRF + d], zsh[d], pv);
            part[td * 5 + q4] = pv;
        }
        __syncthreads();

        // (d) O = Q @ S_prev + A @ V  (per wave: rows [wave*16,+16), 16 cols)
        {
            f32x4 o = (f32x4){0.f, 0.f, 0.f, 0.f};
#pragma unroll
            for (int ks = 0; ks < 2; ++ks) {
                const int ko = ks * 32 + q * 8;                 // k = d
                const bf16x8 aQ = frag8(&Qs[(wave * 16 + la) * LSTRF + ko]);
                const bf16x8 bS = frag8(&St[la * LSTRF + ko]);
                o = __builtin_amdgcn_mfma_f32_16x16x32_bf16(aQ, bS, o, 0, 0, 0);
            }
#pragma unroll
            for (int ks = 0; ks < 2; ++ks) {
                const int ko = ks * 32 + q * 8;                 // k = s
                const bf16x8 aA = frag8(&AtKt[(wave * 16 + la) * LSTRF + ko]);
                const bf16x8 bV = frag8(&Vt[la * LSTRF + ko]);
                o = __builtin_amdgcn_mfma_f32_16x16x32_bf16(aA, bV, o, 0, 0, 0);
            }
#pragma unroll
            for (int r = 0; r < 4; ++r) {
                const int t = wave * 16 + q * 4 + r;
                const float dn = part[t * 5 + 0] + part[t * 5 + 1]
                               + part[t * 5 + 2] + part[t * 5 + 3] + EPSV;
                Ob[gq + (size_t)t * D_MODEL + mh * 16 + la] = f2bf(o[r] / dn);
            }
        }
        __syncthreads();   // At fully consumed

        // (e) LDS->LDS transpose: AtKt[d][t] = Ks[t][d]  (b32 read + b32 write)
#pragma unroll
        for (int i = 0; i < 16; ++i) {
            const int idx = i * 256 + tid;
            const int t = idx >> 6, d = idx & 63;
            AtKt[d * LSTRF + t] = Ks[t * LSTRF + d];
        }
        __syncthreads();

        // (f) S^T[m][d] += sum_t V[t][m] K[t][d]; Z += z partials
        {
            f32x4 su = (f32x4){0.f, 0.f, 0.f, 0.f};
#pragma unroll
            for (int ks = 0; ks < 2; ++ks) {
                const int ko = ks * 32 + q * 8;                 // k = t
                const bf16x8 aV = frag8(&Vt[la * LSTRF + ko]);
                const bf16x8 bK = frag8(&AtKt[(wave * 16 + la) * LSTRF + ko]);
                su = __builtin_amdgcn_mfma_f32_16x16x32_bf16(aV, bK, su, 0, 0, 0);
            }
#pragma unroll
            for (int r = 0; r < 4; ++r)
                St[(q * 4 + r) * LSTRF + wave * 16 + la] += su[r];
        }
        if (tid < 64)
            zsh[tid] += zp[tid * 5 + 0] + zp[tid * 5 + 1]
                      + zp[tid * 5 + 2] + zp[tid * 5 + 3];
        __syncthreads();
    }
}

extern "C" void kernel_launch(void* const* d_in, const int* in_sizes, int n_in,
                              void* d_out, int out_size, void* d_ws, size_t ws_size,
                              hipStream_t stream)
{
    const float* x  = (const float*)d_in[0];
    const float* Wq = (const float*)d_in[1];
    const float* bq = (const float*)d_in[2];
    const float* Wk = (const float*)d_in[3];
    const float* bk = (const float*)d_in[4];
    const float* Wv = (const float*)d_in[5];
    const float* bv = (const float*)d_in[6];
    const float* Wo = (const float*)d_in[7];
    const float* bo = (const float*)d_in[8];
    float* out = (float*)d_out;

    const size_t NE = (size_t)NTOK * D_MODEL;               // 2M elems
    unsigned short* xb  = (unsigned short*)d_ws;            // 2M bf16
    unsigned short* Wt  = xb + NE;                          // 768*256
    unsigned short* Wot = Wt + 768 * 256;                   // 256*256
    unsigned short* Qb  = Wot + 256 * 256;                  // 2M
    unsigned short* Kb  = Qb + NE;                          // 2M
    unsigned short* Vb  = Kb + NE;                          // 2M
    unsigned short* Ob  = Vb + NE;                          // 2M

    convert_kernel<<<NTOK * D_MODEL / 8 / 256 + 64, 256, 0, stream>>>(
        x, Wq, Wk, Wv, Wo, xb, Wt, Wot);
    mfma_gemm_kernel<0><<<(NTOK / 128) * 6, 256, 0, stream>>>(
        xb, Wt, bq, bk, bv, Qb, Kb, Vb);
    scan_kernel<<<NBH * 4, 256, 0, stream>>>(Qb, Kb, Vb, Ob);
    mfma_gemm_kernel<1><<<(NTOK / 128) * 2, 256, 0, stream>>>(
        Ob, Wot, bo, nullptr, nullptr, out, nullptr, nullptr);
}

// Round 10
// 124.435 us; speedup vs baseline: 1.7653x; 1.7653x over previous
//
#include <hip/hip_runtime.h>
#include <hip/hip_bf16.h>

#define D_MODEL 256
#define NHEADS 4
#define DHEAD 64
#define BATCH 4
#define TSEQ 2048
#define CHUNK 64
#define NCHUNK (TSEQ / CHUNK)   // 32
#define NTOK (BATCH * TSEQ)     // 8192
#define NBH (BATCH * NHEADS)    // 16
#define EPSV 1e-6f
#define LSTRF 68                // fp32 LDS row stride (verified)
#define PSTR 36                 // packed-bf16 LDS row stride in uints (144B, 16B-aligned)

typedef __bf16 bf16x8 __attribute__((ext_vector_type(8)));
typedef float f32x4 __attribute__((ext_vector_type(4)));
typedef unsigned short us8 __attribute__((ext_vector_type(8)));

__device__ __forceinline__ float elu1(float a) {
    return a > 0.0f ? a + 1.0f : __expf(a);
}

__device__ __forceinline__ unsigned short f2bf(float f) {
    __hip_bfloat16 h = __float2bfloat16(f);   // RNE
    return __builtin_bit_cast(unsigned short, h);
}

__device__ __forceinline__ float bf2f(unsigned short u) {
    return __bfloat162float(__builtin_bit_cast(__hip_bfloat16, u));
}

// unpack a dword holding 2 bf16 (lo,hi) into 2 fp32 — 2 VALU ops
__device__ __forceinline__ void unpack2(unsigned int u, float& lo, float& hi) {
    lo = __builtin_bit_cast(float, u << 16);
    hi = __builtin_bit_cast(float, u & 0xFFFF0000u);
}

__device__ __forceinline__ void unpack8(uint4 u, float* f) {
    unpack2(u.x, f[0], f[1]);
    unpack2(u.y, f[2], f[3]);
    unpack2(u.z, f[4], f[5]);
    unpack2(u.w, f[6], f[7]);
}

__device__ __forceinline__ unsigned int pack2(float a, float b) {
    return (unsigned int)f2bf(a) | ((unsigned int)f2bf(b) << 16);
}

// Build a bf16x8 MFMA fragment from 8 consecutive fp32 (16B-aligned LDS).
// Verified class (R7): 2x float4 LDS reads + VALU cvt.
__device__ __forceinline__ bf16x8 frag8(const float* p) {
    const float4 x = *reinterpret_cast<const float4*>(p);
    const float4 y = *reinterpret_cast<const float4*>(p + 4);
    us8 u;
    u[0] = f2bf(x.x); u[1] = f2bf(x.y); u[2] = f2bf(x.z); u[3] = f2bf(x.w);
    u[4] = f2bf(y.x); u[5] = f2bf(y.y); u[6] = f2bf(y.z); u[7] = f2bf(y.w);
    return __builtin_bit_cast(bf16x8, u);
}

// async global->LDS, 16B per lane; lds ptr must be wave-uniform base.
__device__ __forceinline__ void gld_lds16(const void* g, void* l) {
    __builtin_amdgcn_global_load_lds(
        (const __attribute__((address_space(1))) void*)g,
        (__attribute__((address_space(3))) void*)l, 16, 0, 0);
}

// ---------------------------------------------------------------------------
// fused converts (R9-verified): blocks [0,1024): x->bf16; rest: W transposes
// ---------------------------------------------------------------------------
__global__ __launch_bounds__(256) void convert_kernel(
    const float* __restrict__ x,
    const float* __restrict__ Wq, const float* __restrict__ Wk,
    const float* __restrict__ Wv, const float* __restrict__ Wo,
    unsigned short* __restrict__ xb,
    unsigned short* __restrict__ Wt, unsigned short* __restrict__ Wot)
{
    const int tid = threadIdx.x;
    if (blockIdx.x < NTOK * D_MODEL / 8 / 256) {
        const int i = (blockIdx.x * 256 + tid) * 8;
        const float4 a = *reinterpret_cast<const float4*>(&x[i]);
        const float4 b = *reinterpret_cast<const float4*>(&x[i + 4]);
        ushort4 u0 = { f2bf(a.x), f2bf(a.y), f2bf(a.z), f2bf(a.w) };
        ushort4 u1 = { f2bf(b.x), f2bf(b.y), f2bf(b.z), f2bf(b.w) };
        *reinterpret_cast<ushort4*>(&xb[i]) = u0;
        *reinterpret_cast<ushort4*>(&xb[i + 4]) = u1;
        return;
    }
    __shared__ float Ls[64][65];
    const int bid = blockIdx.x - NTOK * D_MODEL / 8 / 256;
    const int wi = bid >> 4;
    const int ti = bid & 15;
    const int k0 = (ti >> 2) * 64, n0 = (ti & 3) * 64;
    const float* W = wi == 0 ? Wq : wi == 1 ? Wk : wi == 2 ? Wv : Wo;
#pragma unroll
    for (int i = 0; i < 16; ++i) {
        const int idx = i * 256 + tid;
        const int r = idx >> 6, c = idx & 63;
        Ls[r][c] = W[(size_t)(k0 + r) * D_MODEL + n0 + c];
    }
    __syncthreads();
    unsigned short* outp = (wi < 3) ? (Wt + (size_t)(wi * 256 + n0) * D_MODEL + k0)
                                    : (Wot + (size_t)n0 * D_MODEL + k0);
#pragma unroll
    for (int i = 0; i < 16; ++i) {
        const int idx = i * 256 + tid;
        const int rn = idx >> 6, ck = idx & 63;
        outp[(size_t)rn * D_MODEL + ck] = f2bf(Ls[ck][rn]);
    }
}

// ---------------------------------------------------------------------------
// MFMA bf16 GEMM, m97 structure (verified).
// MODE 0: qkv -> bf16 Q/K/V with elu1 on Q,K.  MODE 1: -> fp32 out.
// ---------------------------------------------------------------------------
template<int MODE>
__global__ __launch_bounds__(256) void mfma_gemm_kernel(
    const unsigned short* __restrict__ A,
    const unsigned short* __restrict__ Bt,
    const float* __restrict__ b0, const float* __restrict__ b1,
    const float* __restrict__ b2,
    void* __restrict__ O0, void* __restrict__ O1, void* __restrict__ O2)
{
    __shared__ __align__(16) unsigned short As[128 * 64];
    __shared__ __align__(16) unsigned short Bs[128 * 64];
    const int tid = threadIdx.x;
    const int wave = tid >> 6, lane = tid & 63;
    const int la = lane & 15, q = lane >> 4;
    const int wm = (wave >> 1) * 64, wn = (wave & 1) * 64;

    int mtile, ntile;
    if (MODE == 0) { ntile = blockIdx.x % 6; mtile = blockIdx.x / 6; }
    else           { ntile = blockIdx.x & 1; mtile = blockIdx.x >> 1; }
    const int m0 = mtile * 128, n0 = ntile * 128;

    const unsigned short* Ab = A  + (size_t)m0 * D_MODEL;
    const unsigned short* Bb = Bt + (size_t)n0 * D_MODEL;

    f32x4 acc[4][4];
#pragma unroll
    for (int i = 0; i < 4; ++i)
#pragma unroll
        for (int j = 0; j < 4; ++j) acc[i][j] = (f32x4){0.f, 0.f, 0.f, 0.f};

    for (int k0 = 0; k0 < D_MODEL; k0 += 64) {
#pragma unroll
        for (int i = 0; i < 4; ++i) {
            const int bslot = i * 256 + wave * 64;
            const int slot = bslot + lane;
            const int m = slot >> 3, s = slot & 7;
            const int g = s ^ (m & 7);
            gld_lds16(Ab + (size_t)m * D_MODEL + k0 + g * 8, &As[bslot * 8]);
            gld_lds16(Bb + (size_t)m * D_MODEL + k0 + g * 8, &Bs[bslot * 8]);
        }
        __syncthreads();

        bf16x8 af[4][2], bfr[4][2];
#pragma unroll
        for (int i = 0; i < 4; ++i) {
#pragma unroll
            for (int kh = 0; kh < 2; ++kh) {
                const int g = kh * 4 + q;
                const int m = wm + i * 16 + la;
                af[i][kh] = *reinterpret_cast<const bf16x8*>(
                    &As[m * 64 + ((g ^ (m & 7)) << 3)]);
                const int n = wn + i * 16 + la;
                bfr[i][kh] = *reinterpret_cast<const bf16x8*>(
                    &Bs[n * 64 + ((g ^ (n & 7)) << 3)]);
            }
        }
#pragma unroll
        for (int mi = 0; mi < 4; ++mi)
#pragma unroll
            for (int ni = 0; ni < 4; ++ni) {
                acc[mi][ni] = __builtin_amdgcn_mfma_f32_16x16x32_bf16(
                    af[mi][0], bfr[ni][0], acc[mi][ni], 0, 0, 0);
                acc[mi][ni] = __builtin_amdgcn_mfma_f32_16x16x32_bf16(
                    af[mi][1], bfr[ni][1], acc[mi][ni], 0, 0, 0);
            }
        __syncthreads();
    }

    // C/D layout: col=lane&15, row=(lane>>4)*4+reg
#pragma unroll
    for (int mi = 0; mi < 4; ++mi) {
#pragma unroll
        for (int ni = 0; ni < 4; ++ni) {
            const int row = m0 + wm + mi * 16 + q * 4;
            const int col = n0 + wn + ni * 16 + la;
            if (MODE == 0) {
                const int which = col >> 8;          // block-uniform
                const int cl = col & 255;
                unsigned short* Out = (unsigned short*)
                    (which == 0 ? O0 : which == 1 ? O1 : O2);
                const float* bias = which == 0 ? b0 : which == 1 ? b1 : b2;
                const int act = (which < 2);
                const float bv = bias[cl];
#pragma unroll
                for (int r = 0; r < 4; ++r) {
                    float v = acc[mi][ni][r] + bv;
                    if (act) v = elu1(v);
                    Out[(size_t)(row + r) * D_MODEL + cl] = f2bf(v);
                }
            } else {
                float* Out = (float*)O0;
                const float bv = b0[col];
#pragma unroll
                for (int r = 0; r < 4; ++r)
                    Out[(size_t)(row + r) * D_MODEL + col] = acc[mi][ni][r] + bv;
            }
        }
    }
}

// ---------------------------------------------------------------------------
// chunksum (R7-verified MFMA compute; NEW uint4 staging):
//   Pt_c[m][d] = sum_t V[t][m] K[t][d]; Z_c[d] = sum_t K[t][d]
// ---------------------------------------------------------------------------
__global__ __launch_bounds__(256) void chunksum_kernel(
    const unsigned short* __restrict__ Kb, const unsigned short* __restrict__ Vb,
    float* __restrict__ Pt, float* __restrict__ Zc)
{
    __shared__ __align__(16) float Ktf[DHEAD * LSTRF];   // Ktf[d][t]
    __shared__ __align__(16) float Vtf[DHEAD * LSTRF];   // Vtf[m][t]
    const int tid = threadIdx.x;
    const int c  = blockIdx.x % NCHUNK;
    const int bh = blockIdx.x / NCHUNK;
    const int b = bh / NHEADS, h = bh % NHEADS;
    const size_t gbase = ((size_t)(b * TSEQ + c * CHUNK)) * D_MODEL + h * DHEAD;

    // staging: uint4 loads (dwordx4 class, = verified float4 class) + unpack
#pragma unroll
    for (int i = 0; i < 2; ++i) {
        const int idx = i * 256 + tid;           // 0..511
        const int t = idx >> 3, e0 = (idx & 7) * 8;
        float kf[8], vf[8];
        unpack8(*reinterpret_cast<const uint4*>(&Kb[gbase + (size_t)t * D_MODEL + e0]), kf);
        unpack8(*reinterpret_cast<const uint4*>(&Vb[gbase + (size_t)t * D_MODEL + e0]), vf);
#pragma unroll
        for (int j = 0; j < 8; ++j) {
            Ktf[(e0 + j) * LSTRF + t] = kf[j];
            Vtf[(e0 + j) * LSTRF + t] = vf[j];
        }
    }
    __syncthreads();

    const int wave = tid >> 6, lane = tid & 63;
    const int la = lane & 15, q = lane >> 4;
    const int wm = (wave >> 1) * 32, wn = (wave & 1) * 32;   // m rows, d cols

    f32x4 acc[2][2];
#pragma unroll
    for (int i = 0; i < 2; ++i)
#pragma unroll
        for (int j = 0; j < 2; ++j) acc[i][j] = (f32x4){0.f, 0.f, 0.f, 0.f};

#pragma unroll
    for (int ks = 0; ks < 2; ++ks) {
        const int ko = ks * 32 + q * 8;                       // k = t
        const bf16x8 a0  = frag8(&Vtf[(wm + la) * LSTRF + ko]);
        const bf16x8 a1  = frag8(&Vtf[(wm + 16 + la) * LSTRF + ko]);
        const bf16x8 bb0 = frag8(&Ktf[(wn + la) * LSTRF + ko]);
        const bf16x8 bb1 = frag8(&Ktf[(wn + 16 + la) * LSTRF + ko]);
        acc[0][0] = __builtin_amdgcn_mfma_f32_16x16x32_bf16(a0, bb0, acc[0][0], 0, 0, 0);
        acc[0][1] = __builtin_amdgcn_mfma_f32_16x16x32_bf16(a0, bb1, acc[0][1], 0, 0, 0);
        acc[1][0] = __builtin_amdgcn_mfma_f32_16x16x32_bf16(a1, bb0, acc[1][0], 0, 0, 0);
        acc[1][1] = __builtin_amdgcn_mfma_f32_16x16x32_bf16(a1, bb1, acc[1][1], 0, 0, 0);
    }

    float* Pb = Pt + (size_t)blockIdx.x * (DHEAD * DHEAD);
#pragma unroll
    for (int mi = 0; mi < 2; ++mi)
#pragma unroll
        for (int ni = 0; ni < 2; ++ni) {
            const int row = wm + mi * 16 + q * 4;   // m
            const int col = wn + ni * 16 + la;      // d
#pragma unroll
            for (int r = 0; r < 4; ++r)
                Pb[(row + r) * DHEAD + col] = acc[mi][ni][r];
        }

    if (tid < DHEAD) {
        float z = 0.f;
        for (int t = 0; t < CHUNK; ++t) z += Ktf[tid * LSTRF + t];
        Zc[(size_t)blockIdx.x * DHEAD + tid] = z;
    }
}

// ---------------------------------------------------------------------------
// chunkout (R7-verified MFMA compute; NEW uint4 staging + INLINE prefix):
//   S_prev^T = sum_{c'<c} Pt_c'  (accumulated per block, packed bf16 in LDS)
//   A = tril(Q K^T);  O[t][m] = (Q S_prev + A V)[t][m] / denom[t] -> bf16
// ---------------------------------------------------------------------------
__global__ __launch_bounds__(256) void chunkout_kernel(
    const unsigned short* __restrict__ Qb, const unsigned short* __restrict__ Kb,
    const unsigned short* __restrict__ Vb,
    const float* __restrict__ Pt, const float* __restrict__ Zc,
    unsigned short* __restrict__ Ob)
{
    __shared__ __align__(16) float Qs[CHUNK * LSTRF];    // Qs[t][d]
    __shared__ __align__(16) float Ks[CHUNK * LSTRF];    // Ks[s][d]
    __shared__ __align__(16) float Vtf[DHEAD * LSTRF];   // Vtf[m][s]
    __shared__ __align__(16) float At[CHUNK * LSTRF];    // At[t][s] masked QK^T
    __shared__ __align__(16) unsigned int Stp[DHEAD * PSTR]; // packed bf16 S^T[m][d]
    __shared__ float zsh[DHEAD];
    __shared__ float dnm[CHUNK];

    const int tid = threadIdx.x;
    const int c  = blockIdx.x % NCHUNK;
    const int bh = blockIdx.x / NCHUNK;
    const int b = bh / NHEADS, h = bh % NHEADS;
    const size_t gbase = ((size_t)(b * TSEQ + c * CHUNK)) * D_MODEL + h * DHEAD;

    // stage Q,K row-major + V transposed (uint4 loads + unpack)
#pragma unroll
    for (int i = 0; i < 2; ++i) {
        const int idx = i * 256 + tid;
        const int t = idx >> 3, e0 = (idx & 7) * 8;
        float qf[8], kf[8], vf[8];
        unpack8(*reinterpret_cast<const uint4*>(&Qb[gbase + (size_t)t * D_MODEL + e0]), qf);
        unpack8(*reinterpret_cast<const uint4*>(&Kb[gbase + (size_t)t * D_MODEL + e0]), kf);
        unpack8(*reinterpret_cast<const uint4*>(&Vb[gbase + (size_t)t * D_MODEL + e0]), vf);
        *reinterpret_cast<float4*>(&Qs[t * LSTRF + e0])     = (float4){qf[0], qf[1], qf[2], qf[3]};
        *reinterpret_cast<float4*>(&Qs[t * LSTRF + e0 + 4]) = (float4){qf[4], qf[5], qf[6], qf[7]};
        *reinterpret_cast<float4*>(&Ks[t * LSTRF + e0])     = (float4){kf[0], kf[1], kf[2], kf[3]};
        *reinterpret_cast<float4*>(&Ks[t * LSTRF + e0 + 4]) = (float4){kf[4], kf[5], kf[6], kf[7]};
#pragma unroll
        for (int j = 0; j < 8; ++j)
            Vtf[(e0 + j) * LSTRF + t] = vf[j];
    }

    // INLINE exclusive prefix: S_prev^T[m][d] = sum_{c'<c} Pt; pack -> Stp
    {
        const int r = tid >> 2, q16 = tid & 3;               // r=m row, 16 d's
        float sacc[16];
#pragma unroll
        for (int k = 0; k < 16; ++k) sacc[k] = 0.f;
        const float* Pb = Pt + (size_t)bh * NCHUNK * (DHEAD * DHEAD)
                             + r * DHEAD + q16 * 16;
        for (int cp = 0; cp < c; ++cp) {
            const float* src = Pb + (size_t)cp * (DHEAD * DHEAD);
#pragma unroll
            for (int k = 0; k < 4; ++k) {
                const float4 v = *reinterpret_cast<const float4*>(&src[k * 4]);
                sacc[k * 4 + 0] += v.x;
                sacc[k * 4 + 1] += v.y;
                sacc[k * 4 + 2] += v.z;
                sacc[k * 4 + 3] += v.w;
            }
        }
        uint4 pa, pb2;
        pa.x  = pack2(sacc[0],  sacc[1]);  pa.y  = pack2(sacc[2],  sacc[3]);
        pa.z  = pack2(sacc[4],  sacc[5]);  pa.w  = pack2(sacc[6],  sacc[7]);
        pb2.x = pack2(sacc[8],  sacc[9]);  pb2.y = pack2(sacc[10], sacc[11]);
        pb2.z = pack2(sacc[12], sacc[13]); pb2.w = pack2(sacc[14], sacc[15]);
        *reinterpret_cast<uint4*>(&Stp[r * PSTR + q16 * 8])     = pa;
        *reinterpret_cast<uint4*>(&Stp[r * PSTR + q16 * 8 + 4]) = pb2;
    }
    // inline Z prefix
    if (tid < DHEAD) {
        float z = 0.f;
        for (int cp = 0; cp < c; ++cp)
            z += Zc[((size_t)bh * NCHUNK + cp) * DHEAD + tid];
        zsh[tid] = z;
    }
    __syncthreads();

    const int wave = tid >> 6, lane = tid & 63;
    const int la = lane & 15, q = lane >> 4;
    const int wt = (wave >> 1) * 32, wn = (wave & 1) * 32;

    // phase 1: A = Q K^T
    f32x4 acc[2][2];
#pragma unroll
    for (int i = 0; i < 2; ++i)
#pragma unroll
        for (int j = 0; j < 2; ++j) acc[i][j] = (f32x4){0.f, 0.f, 0.f, 0.f};
#pragma unroll
    for (int ks = 0; ks < 2; ++ks) {
        const int ko = ks * 32 + q * 8;
        const bf16x8 a0  = frag8(&Qs[(wt + la) * LSTRF + ko]);
        const bf16x8 a1  = frag8(&Qs[(wt + 16 + la) * LSTRF + ko]);
        const bf16x8 bb0 = frag8(&Ks[(wn + la) * LSTRF + ko]);
        const bf16x8 bb1 = frag8(&Ks[(wn + 16 + la) * LSTRF + ko]);
        acc[0][0] = __builtin_amdgcn_mfma_f32_16x16x32_bf16(a0, bb0, acc[0][0], 0, 0, 0);
        acc[0][1] = __builtin_amdgcn_mfma_f32_16x16x32_bf16(a0, bb1, acc[0][1], 0, 0, 0);
        acc[1][0] = __builtin_amdgcn_mfma_f32_16x16x32_bf16(a1, bb0, acc[1][0], 0, 0, 0);
        acc[1][1] = __builtin_amdgcn_mfma_f32_16x16x32_bf16(a1, bb1, acc[1][1], 0, 0, 0);
    }
#pragma unroll
    for (int mi = 0; mi < 2; ++mi)
#pragma unroll
        for (int ni = 0; ni < 2; ++ni) {
            const int t0 = wt + mi * 16 + q * 4;
            const int s  = wn + ni * 16 + la;
#pragma unroll
            for (int r = 0; r < 4; ++r)
                At[(t0 + r) * LSTRF + s] = (s <= t0 + r) ? acc[mi][ni][r] : 0.f;
        }
    __syncthreads();

    // phase 2: denom[t] = rowsum(A) + Q . Z_prev + eps
    if (tid < CHUNK) {
        float dv = 0.f;
        for (int s = 0; s < CHUNK; ++s) dv += At[tid * LSTRF + s];
        for (int d = 0; d < DHEAD; ++d) dv = fmaf(Qs[tid * LSTRF + d], zsh[d], dv);
        dnm[tid] = dv + EPSV;
    }
    __syncthreads();

    // phase 3: O = Q @ S_prev + A @ V
    f32x4 o[2][2];
#pragma unroll
    for (int i = 0; i < 2; ++i)
#pragma unroll
        for (int j = 0; j < 2; ++j) o[i][j] = (f32x4){0.f, 0.f, 0.f, 0.f};
#pragma unroll
    for (int ks = 0; ks < 2; ++ks) {
        const int ko = ks * 32 + q * 8;                       // k = d
        const bf16x8 a0  = frag8(&Qs[(wt + la) * LSTRF + ko]);
        const bf16x8 a1  = frag8(&Qs[(wt + 16 + la) * LSTRF + ko]);
        const bf16x8 bb0 = __builtin_bit_cast(bf16x8,
            *reinterpret_cast<const uint4*>(&Stp[(wn + la) * PSTR + ks * 16 + q * 4]));
        const bf16x8 bb1 = __builtin_bit_cast(bf16x8,
            *reinterpret_cast<const uint4*>(&Stp[(wn + 16 + la) * PSTR + ks * 16 + q * 4]));
        o[0][0] = __builtin_amdgcn_mfma_f32_16x16x32_bf16(a0, bb0, o[0][0], 0, 0, 0);
        o[0][1] = __builtin_amdgcn_mfma_f32_16x16x32_bf16(a0, bb1, o[0][1], 0, 0, 0);
        o[1][0] = __builtin_amdgcn_mfma_f32_16x16x32_bf16(a1, bb0, o[1][0], 0, 0, 0);
        o[1][1] = __builtin_amdgcn_mfma_f32_16x16x32_bf16(a1, bb1, o[1][1], 0, 0, 0);
    }
#pragma unroll
    for (int ks = 0; ks < 2; ++ks) {
        const int ko = ks * 32 + q * 8;                       // k = s
        const bf16x8 a0  = frag8(&At[(wt + la) * LSTRF + ko]);
        const bf16x8 a1  = frag8(&At[(wt + 16 + la) * LSTRF + ko]);
        const bf16x8 bb0 = frag8(&Vtf[(wn + la) * LSTRF + ko]);
        const bf16x8 bb1 = frag8(&Vtf[(wn + 16 + la) * LSTRF + ko]);
        o[0][0] = __builtin_amdgcn_mfma_f32_16x16x32_bf16(a0, bb0, o[0][0], 0, 0, 0);
        o[0][1] = __builtin_amdgcn_mfma_f32_16x16x32_bf16(a0, bb1, o[0][1], 0, 0, 0);
        o[1][0] = __builtin_amdgcn_mfma_f32_16x16x32_bf16(a1, bb0, o[1][0], 0, 0, 0);
        o[1][1] = __builtin_amdgcn_mfma_f32_16x16x32_bf16(a1, bb1, o[1][1], 0, 0, 0);
    }

    // epilogue: divide + bf16 scalar stores (verified class)
#pragma unroll
    for (int mi = 0; mi < 2; ++mi)
#pragma unroll
        for (int ni = 0; ni < 2; ++ni) {
            const int t0 = wt + mi * 16 + q * 4;
            const int m  = wn + ni * 16 + la;
#pragma unroll
            for (int r = 0; r < 4; ++r) {
                const float v = o[mi][ni][r] / dnm[t0 + r];
                Ob[gbase + (size_t)(t0 + r) * D_MODEL + m] = f2bf(v);
            }
        }
}

extern "C" void kernel_launch(void* const* d_in, const int* in_sizes, int n_in,
                              void* d_out, int out_size, void* d_ws, size_t ws_size,
                              hipStream_t stream)
{
    const float* x  = (const float*)d_in[0];
    const float* Wq = (const float*)d_in[1];
    const float* bq = (const float*)d_in[2];
    const float* Wk = (const float*)d_in[3];
    const float* bk = (const float*)d_in[4];
    const float* Wv = (const float*)d_in[5];
    const float* bv = (const float*)d_in[6];
    const float* Wo = (const float*)d_in[7];
    const float* bo = (const float*)d_in[8];
    float* out = (float*)d_out;

    const size_t NE = (size_t)NTOK * D_MODEL;               // 2M elems
    unsigned short* xb  = (unsigned short*)d_ws;            // 2M bf16
    unsigned short* Wt  = xb + NE;                          // 768*256
    unsigned short* Wot = Wt + 768 * 256;                   // 256*256
    unsigned short* Qb  = Wot + 256 * 256;                  // 2M
    unsigned short* Kb  = Qb + NE;                          // 2M
    unsigned short* Vb  = Kb + NE;                          // 2M
    unsigned short* Ob  = Vb + NE;                          // 2M
    float* P = (float*)(Ob + NE);                           // 16*32*4096 f32 (8MB)
    float* Z = P + (size_t)NBH * NCHUNK * DHEAD * DHEAD;    // 16*32*64 f32

    convert_kernel<<<NTOK * D_MODEL / 8 / 256 + 64, 256, 0, stream>>>(
        x, Wq, Wk, Wv, Wo, xb, Wt, Wot);
    mfma_gemm_kernel<0><<<(NTOK / 128) * 6, 256, 0, stream>>>(
        xb, Wt, bq, bk, bv, Qb, Kb, Vb);
    chunksum_kernel<<<NBH * NCHUNK, 256, 0, stream>>>(Kb, Vb, P, Z);
    chunkout_kernel<<<NBH * NCHUNK, 256, 0, stream>>>(Qb, Kb, Vb, P, Z, Ob);
    mfma_gemm_kernel<1><<<(NTOK / 128) * 2, 256, 0, stream>>>(
        Ob, Wot, bo, nullptr, nullptr, out, nullptr, nullptr);
}

// Round 11
// 115.366 us; speedup vs baseline: 1.9040x; 1.0786x over previous
//
#include <hip/hip_runtime.h>
#include <hip/hip_bf16.h>

#define D_MODEL 256
#define NHEADS 4
#define DHEAD 64
#define BATCH 4
#define TSEQ 2048
#define CHUNK 64
#define NCHUNK (TSEQ / CHUNK)   // 32
#define NTOK (BATCH * TSEQ)     // 8192
#define NBH (BATCH * NHEADS)    // 16
#define EPSV 1e-6f
#define LSTRF 68                // fp32 LDS row stride (verified)

typedef __bf16 bf16x8 __attribute__((ext_vector_type(8)));
typedef float f32x4 __attribute__((ext_vector_type(4)));
typedef unsigned short us8 __attribute__((ext_vector_type(8)));

__device__ __forceinline__ float elu1(float a) {
    return a > 0.0f ? a + 1.0f : __expf(a);
}

__device__ __forceinline__ unsigned short f2bf(float f) {
    __hip_bfloat16 h = __float2bfloat16(f);   // RNE
    return __builtin_bit_cast(unsigned short, h);
}

__device__ __forceinline__ float bf2f(unsigned short u) {
    return __bfloat162float(__builtin_bit_cast(__hip_bfloat16, u));
}

// unpack a dword holding 2 bf16 (lo,hi) into 2 fp32 — 2 VALU ops
__device__ __forceinline__ void unpack2(unsigned int u, float& lo, float& hi) {
    lo = __builtin_bit_cast(float, u << 16);
    hi = __builtin_bit_cast(float, u & 0xFFFF0000u);
}

__device__ __forceinline__ void unpack8(uint4 u, float* f) {
    unpack2(u.x, f[0], f[1]);
    unpack2(u.y, f[2], f[3]);
    unpack2(u.z, f[4], f[5]);
    unpack2(u.w, f[6], f[7]);
}

// Build a bf16x8 MFMA fragment from 8 consecutive fp32 (16B-aligned).
// Verified class (R7): 2x float4 reads (LDS or global) + VALU cvt.
__device__ __forceinline__ bf16x8 frag8(const float* p) {
    const float4 x = *reinterpret_cast<const float4*>(p);
    const float4 y = *reinterpret_cast<const float4*>(p + 4);
    us8 u;
    u[0] = f2bf(x.x); u[1] = f2bf(x.y); u[2] = f2bf(x.z); u[3] = f2bf(x.w);
    u[4] = f2bf(y.x); u[5] = f2bf(y.y); u[6] = f2bf(y.z); u[7] = f2bf(y.w);
    return __builtin_bit_cast(bf16x8, u);
}

// async global->LDS, 16B per lane; lds ptr must be wave-uniform base.
__device__ __forceinline__ void gld_lds16(const void* g, void* l) {
    __builtin_amdgcn_global_load_lds(
        (const __attribute__((address_space(1))) void*)g,
        (__attribute__((address_space(3))) void*)l, 16, 0, 0);
}

// ---------------------------------------------------------------------------
// fused converts (R9/R10-verified): blocks [0,1024): x->bf16; rest: W^T
// ---------------------------------------------------------------------------
__global__ __launch_bounds__(256) void convert_kernel(
    const float* __restrict__ x,
    const float* __restrict__ Wq, const float* __restrict__ Wk,
    const float* __restrict__ Wv, const float* __restrict__ Wo,
    unsigned short* __restrict__ xb,
    unsigned short* __restrict__ Wt, unsigned short* __restrict__ Wot)
{
    const int tid = threadIdx.x;
    if (blockIdx.x < NTOK * D_MODEL / 8 / 256) {
        const int i = (blockIdx.x * 256 + tid) * 8;
        const float4 a = *reinterpret_cast<const float4*>(&x[i]);
        const float4 b = *reinterpret_cast<const float4*>(&x[i + 4]);
        ushort4 u0 = { f2bf(a.x), f2bf(a.y), f2bf(a.z), f2bf(a.w) };
        ushort4 u1 = { f2bf(b.x), f2bf(b.y), f2bf(b.z), f2bf(b.w) };
        *reinterpret_cast<ushort4*>(&xb[i]) = u0;
        *reinterpret_cast<ushort4*>(&xb[i + 4]) = u1;
        return;
    }
    __shared__ float Ls[64][65];
    const int bid = blockIdx.x - NTOK * D_MODEL / 8 / 256;
    const int wi = bid >> 4;
    const int ti = bid & 15;
    const int k0 = (ti >> 2) * 64, n0 = (ti & 3) * 64;
    const float* W = wi == 0 ? Wq : wi == 1 ? Wk : wi == 2 ? Wv : Wo;
#pragma unroll
    for (int i = 0; i < 16; ++i) {
        const int idx = i * 256 + tid;
        const int r = idx >> 6, c = idx & 63;
        Ls[r][c] = W[(size_t)(k0 + r) * D_MODEL + n0 + c];
    }
    __syncthreads();
    unsigned short* outp = (wi < 3) ? (Wt + (size_t)(wi * 256 + n0) * D_MODEL + k0)
                                    : (Wot + (size_t)n0 * D_MODEL + k0);
#pragma unroll
    for (int i = 0; i < 16; ++i) {
        const int idx = i * 256 + tid;
        const int rn = idx >> 6, ck = idx & 63;
        outp[(size_t)rn * D_MODEL + ck] = f2bf(Ls[ck][rn]);
    }
}

// ---------------------------------------------------------------------------
// MFMA bf16 GEMM, m97 structure (verified).
// MODE 0: qkv -> bf16 Q/K/V with elu1 on Q,K.  MODE 1: -> fp32 out.
// ---------------------------------------------------------------------------
template<int MODE>
__global__ __launch_bounds__(256) void mfma_gemm_kernel(
    const unsigned short* __restrict__ A,
    const unsigned short* __restrict__ Bt,
    const float* __restrict__ b0, const float* __restrict__ b1,
    const float* __restrict__ b2,
    void* __restrict__ O0, void* __restrict__ O1, void* __restrict__ O2)
{
    __shared__ __align__(16) unsigned short As[128 * 64];
    __shared__ __align__(16) unsigned short Bs[128 * 64];
    const int tid = threadIdx.x;
    const int wave = tid >> 6, lane = tid & 63;
    const int la = lane & 15, q = lane >> 4;
    const int wm = (wave >> 1) * 64, wn = (wave & 1) * 64;

    int mtile, ntile;
    if (MODE == 0) { ntile = blockIdx.x % 6; mtile = blockIdx.x / 6; }
    else           { ntile = blockIdx.x & 1; mtile = blockIdx.x >> 1; }
    const int m0 = mtile * 128, n0 = ntile * 128;

    const unsigned short* Ab = A  + (size_t)m0 * D_MODEL;
    const unsigned short* Bb = Bt + (size_t)n0 * D_MODEL;

    f32x4 acc[4][4];
#pragma unroll
    for (int i = 0; i < 4; ++i)
#pragma unroll
        for (int j = 0; j < 4; ++j) acc[i][j] = (f32x4){0.f, 0.f, 0.f, 0.f};

    for (int k0 = 0; k0 < D_MODEL; k0 += 64) {
#pragma unroll
        for (int i = 0; i < 4; ++i) {
            const int bslot = i * 256 + wave * 64;
            const int slot = bslot + lane;
            const int m = slot >> 3, s = slot & 7;
            const int g = s ^ (m & 7);
            gld_lds16(Ab + (size_t)m * D_MODEL + k0 + g * 8, &As[bslot * 8]);
            gld_lds16(Bb + (size_t)m * D_MODEL + k0 + g * 8, &Bs[bslot * 8]);
        }
        __syncthreads();

        bf16x8 af[4][2], bfr[4][2];
#pragma unroll
        for (int i = 0; i < 4; ++i) {
#pragma unroll
            for (int kh = 0; kh < 2; ++kh) {
                const int g = kh * 4 + q;
                const int m = wm + i * 16 + la;
                af[i][kh] = *reinterpret_cast<const bf16x8*>(
                    &As[m * 64 + ((g ^ (m & 7)) << 3)]);
                const int n = wn + i * 16 + la;
                bfr[i][kh] = *reinterpret_cast<const bf16x8*>(
                    &Bs[n * 64 + ((g ^ (n & 7)) << 3)]);
            }
        }
#pragma unroll
        for (int mi = 0; mi < 4; ++mi)
#pragma unroll
            for (int ni = 0; ni < 4; ++ni) {
                acc[mi][ni] = __builtin_amdgcn_mfma_f32_16x16x32_bf16(
                    af[mi][0], bfr[ni][0], acc[mi][ni], 0, 0, 0);
                acc[mi][ni] = __builtin_amdgcn_mfma_f32_16x16x32_bf16(
                    af[mi][1], bfr[ni][1], acc[mi][ni], 0, 0, 0);
            }
        __syncthreads();
    }

    // C/D layout: col=lane&15, row=(lane>>4)*4+reg
#pragma unroll
    for (int mi = 0; mi < 4; ++mi) {
#pragma unroll
        for (int ni = 0; ni < 4; ++ni) {
            const int row = m0 + wm + mi * 16 + q * 4;
            const int col = n0 + wn + ni * 16 + la;
            if (MODE == 0) {
                const int which = col >> 8;          // block-uniform
                const int cl = col & 255;
                unsigned short* Out = (unsigned short*)
                    (which == 0 ? O0 : which == 1 ? O1 : O2);
                const float* bias = which == 0 ? b0 : which == 1 ? b1 : b2;
                const int act = (which < 2);
                const float bv = bias[cl];
#pragma unroll
                for (int r = 0; r < 4; ++r) {
                    float v = acc[mi][ni][r] + bv;
                    if (act) v = elu1(v);
                    Out[(size_t)(row + r) * D_MODEL + cl] = f2bf(v);
                }
            } else {
                float* Out = (float*)O0;
                const float bv = b0[col];
#pragma unroll
                for (int r = 0; r < 4; ++r)
                    Out[(size_t)(row + r) * D_MODEL + col] = acc[mi][ni][r] + bv;
            }
        }
    }
}

// ---------------------------------------------------------------------------
// chunksum (R10-verified): Pt_c[m][d] = sum_t V[t][m] K[t][d]; Z_c[d].
// uint4 staging + transpose-scatter; MFMA compute.
// ---------------------------------------------------------------------------
__global__ __launch_bounds__(256) void chunksum_kernel(
    const unsigned short* __restrict__ Kb, const unsigned short* __restrict__ Vb,
    float* __restrict__ Pt, float* __restrict__ Zc)
{
    __shared__ __align__(16) float Ktf[DHEAD * LSTRF];   // Ktf[d][t]
    __shared__ __align__(16) float Vtf[DHEAD * LSTRF];   // Vtf[m][t]
    const int tid = threadIdx.x;
    const int c  = blockIdx.x % NCHUNK;
    const int bh = blockIdx.x / NCHUNK;
    const int b = bh / NHEADS, h = bh % NHEADS;
    const size_t gbase = ((size_t)(b * TSEQ + c * CHUNK)) * D_MODEL + h * DHEAD;

#pragma unroll
    for (int i = 0; i < 2; ++i) {
        const int idx = i * 256 + tid;           // 0..511
        const int t = idx >> 3, e0 = (idx & 7) * 8;
        float kf[8], vf[8];
        unpack8(*reinterpret_cast<const uint4*>(&Kb[gbase + (size_t)t * D_MODEL + e0]), kf);
        unpack8(*reinterpret_cast<const uint4*>(&Vb[gbase + (size_t)t * D_MODEL + e0]), vf);
#pragma unroll
        for (int j = 0; j < 8; ++j) {
            Ktf[(e0 + j) * LSTRF + t] = kf[j];
            Vtf[(e0 + j) * LSTRF + t] = vf[j];
        }
    }
    __syncthreads();

    const int wave = tid >> 6, lane = tid & 63;
    const int la = lane & 15, q = lane >> 4;
    const int wm = (wave >> 1) * 32, wn = (wave & 1) * 32;   // m rows, d cols

    f32x4 acc[2][2];
#pragma unroll
    for (int i = 0; i < 2; ++i)
#pragma unroll
        for (int j = 0; j < 2; ++j) acc[i][j] = (f32x4){0.f, 0.f, 0.f, 0.f};

#pragma unroll
    for (int ks = 0; ks < 2; ++ks) {
        const int ko = ks * 32 + q * 8;                       // k = t
        const bf16x8 a0  = frag8(&Vtf[(wm + la) * LSTRF + ko]);
        const bf16x8 a1  = frag8(&Vtf[(wm + 16 + la) * LSTRF + ko]);
        const bf16x8 bb0 = frag8(&Ktf[(wn + la) * LSTRF + ko]);
        const bf16x8 bb1 = frag8(&Ktf[(wn + 16 + la) * LSTRF + ko]);
        acc[0][0] = __builtin_amdgcn_mfma_f32_16x16x32_bf16(a0, bb0, acc[0][0], 0, 0, 0);
        acc[0][1] = __builtin_amdgcn_mfma_f32_16x16x32_bf16(a0, bb1, acc[0][1], 0, 0, 0);
        acc[1][0] = __builtin_amdgcn_mfma_f32_16x16x32_bf16(a1, bb0, acc[1][0], 0, 0, 0);
        acc[1][1] = __builtin_amdgcn_mfma_f32_16x16x32_bf16(a1, bb1, acc[1][1], 0, 0, 0);
    }

    float* Pb = Pt + (size_t)blockIdx.x * (DHEAD * DHEAD);
#pragma unroll
    for (int mi = 0; mi < 2; ++mi)
#pragma unroll
        for (int ni = 0; ni < 2; ++ni) {
            const int row = wm + mi * 16 + q * 4;   // m
            const int col = wn + ni * 16 + la;      // d
#pragma unroll
            for (int r = 0; r < 4; ++r)
                Pb[(row + r) * DHEAD + col] = acc[mi][ni][r];
        }

    if (tid < DHEAD) {
        float z = 0.f;
        for (int t = 0; t < CHUNK; ++t) z += Ktf[tid * LSTRF + t];
        Zc[(size_t)blockIdx.x * DHEAD + tid] = z;
    }
}

// ---------------------------------------------------------------------------
// prefix (R7-verified): exclusive scan over chunks, register-buffered.
// ---------------------------------------------------------------------------
__global__ __launch_bounds__(256) void prefix_kernel(
    float* __restrict__ P, float* __restrict__ Zc)
{
    const int tid = threadIdx.x;
    if (blockIdx.x < NBH * 16) {
        const int bh = blockIdx.x >> 4;
        const int e = ((blockIdx.x & 15) << 8) + tid;
        const size_t base = (size_t)bh * NCHUNK * (DHEAD * DHEAD) + e;
        float v[NCHUNK];
#pragma unroll
        for (int c = 0; c < NCHUNK; ++c) v[c] = P[base + (size_t)c * (DHEAD * DHEAD)];
        float s = 0.f;
#pragma unroll
        for (int c = 0; c < NCHUNK; ++c) {
            const float t = v[c];
            P[base + (size_t)c * (DHEAD * DHEAD)] = s;
            s += t;
        }
    } else {
        const int j = ((int)(blockIdx.x - NBH * 16) << 8) + tid;
        if (j < NBH * DHEAD) {
            const int bh = j >> 6, d = j & 63;
            float v[NCHUNK];
#pragma unroll
            for (int c = 0; c < NCHUNK; ++c) v[c] = Zc[(bh * NCHUNK + c) * DHEAD + d];
            float s = 0.f;
#pragma unroll
            for (int c = 0; c < NCHUNK; ++c) {
                const float t = v[c];
                Zc[(bh * NCHUNK + c) * DHEAD + d] = s;
                s += t;
            }
        }
    }
}

// ---------------------------------------------------------------------------
// chunkout: R7-verified MFMA compute + R10-verified uint4 staging.
// Pt is exclusive-scanned S_prev^T[m][d]; B-frags read from GLOBAL (R7 class).
// ---------------------------------------------------------------------------
__global__ __launch_bounds__(256) void chunkout_kernel(
    const unsigned short* __restrict__ Qb, const unsigned short* __restrict__ Kb,
    const unsigned short* __restrict__ Vb,
    const float* __restrict__ Pt, const float* __restrict__ Zx,
    unsigned short* __restrict__ Ob)
{
    __shared__ __align__(16) float Qs[CHUNK * LSTRF];    // Qs[t][d]
    __shared__ __align__(16) float Ks[CHUNK * LSTRF];    // Ks[s][d]
    __shared__ __align__(16) float Vtf[DHEAD * LSTRF];   // Vtf[m][s]
    __shared__ __align__(16) float At[CHUNK * LSTRF];    // At[t][s] masked QK^T
    __shared__ float zsh[DHEAD];
    __shared__ float dnm[CHUNK];

    const int tid = threadIdx.x;
    const int c  = blockIdx.x % NCHUNK;
    const int bh = blockIdx.x / NCHUNK;
    const int b = bh / NHEADS, h = bh % NHEADS;
    const size_t gbase = ((size_t)(b * TSEQ + c * CHUNK)) * D_MODEL + h * DHEAD;
    const float* Pp = Pt + (size_t)blockIdx.x * (DHEAD * DHEAD);

    // stage Q,K row-major + V transposed (uint4 loads + unpack; R10-verified)
#pragma unroll
    for (int i = 0; i < 2; ++i) {
        const int idx = i * 256 + tid;
        const int t = idx >> 3, e0 = (idx & 7) * 8;
        float qf[8], kf[8], vf[8];
        unpack8(*reinterpret_cast<const uint4*>(&Qb[gbase + (size_t)t * D_MODEL + e0]), qf);
        unpack8(*reinterpret_cast<const uint4*>(&Kb[gbase + (size_t)t * D_MODEL + e0]), kf);
        unpack8(*reinterpret_cast<const uint4*>(&Vb[gbase + (size_t)t * D_MODEL + e0]), vf);
        *reinterpret_cast<float4*>(&Qs[t * LSTRF + e0])     = (float4){qf[0], qf[1], qf[2], qf[3]};
        *reinterpret_cast<float4*>(&Qs[t * LSTRF + e0 + 4]) = (float4){qf[4], qf[5], qf[6], qf[7]};
        *reinterpret_cast<float4*>(&Ks[t * LSTRF + e0])     = (float4){kf[0], kf[1], kf[2], kf[3]};
        *reinterpret_cast<float4*>(&Ks[t * LSTRF + e0 + 4]) = (float4){kf[4], kf[5], kf[6], kf[7]};
#pragma unroll
        for (int j = 0; j < 8; ++j)
            Vtf[(e0 + j) * LSTRF + t] = vf[j];
    }
    if (tid < DHEAD)
        zsh[tid] = Zx[((size_t)bh * NCHUNK + c) * DHEAD + tid];
    __syncthreads();

    const int wave = tid >> 6, lane = tid & 63;
    const int la = lane & 15, q = lane >> 4;
    const int wt = (wave >> 1) * 32, wn = (wave & 1) * 32;

    // phase 1: A = Q K^T
    f32x4 acc[2][2];
#pragma unroll
    for (int i = 0; i < 2; ++i)
#pragma unroll
        for (int j = 0; j < 2; ++j) acc[i][j] = (f32x4){0.f, 0.f, 0.f, 0.f};
#pragma unroll
    for (int ks = 0; ks < 2; ++ks) {
        const int ko = ks * 32 + q * 8;
        const bf16x8 a0  = frag8(&Qs[(wt + la) * LSTRF + ko]);
        const bf16x8 a1  = frag8(&Qs[(wt + 16 + la) * LSTRF + ko]);
        const bf16x8 bb0 = frag8(&Ks[(wn + la) * LSTRF + ko]);
        const bf16x8 bb1 = frag8(&Ks[(wn + 16 + la) * LSTRF + ko]);
        acc[0][0] = __builtin_amdgcn_mfma_f32_16x16x32_bf16(a0, bb0, acc[0][0], 0, 0, 0);
        acc[0][1] = __builtin_amdgcn_mfma_f32_16x16x32_bf16(a0, bb1, acc[0][1], 0, 0, 0);
        acc[1][0] = __builtin_amdgcn_mfma_f32_16x16x32_bf16(a1, bb0, acc[1][0], 0, 0, 0);
        acc[1][1] = __builtin_amdgcn_mfma_f32_16x16x32_bf16(a1, bb1, acc[1][1], 0, 0, 0);
    }
#pragma unroll
    for (int mi = 0; mi < 2; ++mi)
#pragma unroll
        for (int ni = 0; ni < 2; ++ni) {
            const int t0 = wt + mi * 16 + q * 4;
            const int s  = wn + ni * 16 + la;
#pragma unroll
            for (int r = 0; r < 4; ++r)
                At[(t0 + r) * LSTRF + s] = (s <= t0 + r) ? acc[mi][ni][r] : 0.f;
        }
    __syncthreads();

    // phase 2: denom[t] = rowsum(A) + Q . Z_prev + eps
    if (tid < CHUNK) {
        float dv = 0.f;
        for (int s = 0; s < CHUNK; ++s) dv += At[tid * LSTRF + s];
        for (int d = 0; d < DHEAD; ++d) dv = fmaf(Qs[tid * LSTRF + d], zsh[d], dv);
        dnm[tid] = dv + EPSV;
    }
    __syncthreads();

    // phase 3: O = Q @ S_prev + A @ V
    f32x4 o[2][2];
#pragma unroll
    for (int i = 0; i < 2; ++i)
#pragma unroll
        for (int j = 0; j < 2; ++j) o[i][j] = (f32x4){0.f, 0.f, 0.f, 0.f};
#pragma unroll
    for (int ks = 0; ks < 2; ++ks) {
        const int ko = ks * 32 + q * 8;                       // k = d
        const bf16x8 a0  = frag8(&Qs[(wt + la) * LSTRF + ko]);
        const bf16x8 a1  = frag8(&Qs[(wt + 16 + la) * LSTRF + ko]);
        const bf16x8 bb0 = frag8(&Pp[(wn + la) * DHEAD + ko]);        // global
        const bf16x8 bb1 = frag8(&Pp[(wn + 16 + la) * DHEAD + ko]);   // global
        o[0][0] = __builtin_amdgcn_mfma_f32_16x16x32_bf16(a0, bb0, o[0][0], 0, 0, 0);
        o[0][1] = __builtin_amdgcn_mfma_f32_16x16x32_bf16(a0, bb1, o[0][1], 0, 0, 0);
        o[1][0] = __builtin_amdgcn_mfma_f32_16x16x32_bf16(a1, bb0, o[1][0], 0, 0, 0);
        o[1][1] = __builtin_amdgcn_mfma_f32_16x16x32_bf16(a1, bb1, o[1][1], 0, 0, 0);
    }
#pragma unroll
    for (int ks = 0; ks < 2; ++ks) {
        const int ko = ks * 32 + q * 8;                       // k = s
        const bf16x8 a0  = frag8(&At[(wt + la) * LSTRF + ko]);
        const bf16x8 a1  = frag8(&At[(wt + 16 + la) * LSTRF + ko]);
        const bf16x8 bb0 = frag8(&Vtf[(wn + la) * LSTRF + ko]);
        const bf16x8 bb1 = frag8(&Vtf[(wn + 16 + la) * LSTRF + ko]);
        o[0][0] = __builtin_amdgcn_mfma_f32_16x16x32_bf16(a0, bb0, o[0][0], 0, 0, 0);
        o[0][1] = __builtin_amdgcn_mfma_f32_16x16x32_bf16(a0, bb1, o[0][1], 0, 0, 0);
        o[1][0] = __builtin_amdgcn_mfma_f32_16x16x32_bf16(a1, bb0, o[1][0], 0, 0, 0);
        o[1][1] = __builtin_amdgcn_mfma_f32_16x16x32_bf16(a1, bb1, o[1][1], 0, 0, 0);
    }

    // epilogue: divide + bf16 scalar stores (verified class)
#pragma unroll
    for (int mi = 0; mi < 2; ++mi)
#pragma unroll
        for (int ni = 0; ni < 2; ++ni) {
            const int t0 = wt + mi * 16 + q * 4;
            const int m  = wn + ni * 16 + la;
#pragma unroll
            for (int r = 0; r < 4; ++r) {
                const float v = o[mi][ni][r] / dnm[t0 + r];
                Ob[gbase + (size_t)(t0 + r) * D_MODEL + m] = f2bf(v);
            }
        }
}

extern "C" void kernel_launch(void* const* d_in, const int* in_sizes, int n_in,
                              void* d_out, int out_size, void* d_ws, size_t ws_size,
                              hipStream_t stream)
{
    const float* x  = (const float*)d_in[0];
    const float* Wq = (const float*)d_in[1];
    const float* bq = (const float*)d_in[2];
    const float* Wk = (const float*)d_in[3];
    const float* bk = (const float*)d_in[4];
    const float* Wv = (const float*)d_in[5];
    const float* bv = (const float*)d_in[6];
    const float* Wo = (const float*)d_in[7];
    const float* bo = (const float*)d_in[8];
    float* out = (float*)d_out;

    const size_t NE = (size_t)NTOK * D_MODEL;               // 2M elems
    unsigned short* xb  = (unsigned short*)d_ws;            // 2M bf16
    unsigned short* Wt  = xb + NE;                          // 768*256
    unsigned short* Wot = Wt + 768 * 256;                   // 256*256
    unsigned short* Qb  = Wot + 256 * 256;                  // 2M
    unsigned short* Kb  = Qb + NE;                          // 2M
    unsigned short* Vb  = Kb + NE;                          // 2M
    unsigned short* Ob  = Vb + NE;                          // 2M
    float* P = (float*)(Ob + NE);                           // 16*32*4096 f32 (8MB)
    float* Z = P + (size_t)NBH * NCHUNK * DHEAD * DHEAD;    // 16*32*64 f32

    convert_kernel<<<NTOK * D_MODEL / 8 / 256 + 64, 256, 0, stream>>>(
        x, Wq, Wk, Wv, Wo, xb, Wt, Wot);
    mfma_gemm_kernel<0><<<(NTOK / 128) * 6, 256, 0, stream>>>(
        xb, Wt, bq, bk, bv, Qb, Kb, Vb);
    chunksum_kernel<<<NBH * NCHUNK, 256, 0, stream>>>(Kb, Vb, P, Z);
    prefix_kernel<<<NBH * 16 + 4, 256, 0, stream>>>(P, Z);
    chunkout_kernel<<<NBH * NCHUNK, 256, 0, stream>>>(Qb, Kb, Vb, P, Z, Ob);
    mfma_gemm_kernel<1><<<(NTOK / 128) * 2, 256, 0, stream>>>(
        Ob, Wot, bo, nullptr, nullptr, out, nullptr, nullptr);
}

// Round 12
// 111.552 us; speedup vs baseline: 1.9691x; 1.0342x over previous
//
#include <hip/hip_runtime.h>
#include <hip/hip_bf16.h>

#define D_MODEL 256
#define NHEADS 4
#define DHEAD 64
#define BATCH 4
#define TSEQ 2048
#define CHUNK 64
#define NCHUNK (TSEQ / CHUNK)   // 32
#define NTOK (BATCH * TSEQ)     // 8192
#define NBH (BATCH * NHEADS)    // 16
#define EPSV 1e-6f
#define LSTRF 68                // fp32 LDS row stride (verified)

typedef __bf16 bf16x8 __attribute__((ext_vector_type(8)));
typedef float f32x4 __attribute__((ext_vector_type(4)));
typedef unsigned short us8 __attribute__((ext_vector_type(8)));

__device__ __forceinline__ float elu1(float a) {
    return a > 0.0f ? a + 1.0f : __expf(a);
}

__device__ __forceinline__ unsigned short f2bf(float f) {
    __hip_bfloat16 h = __float2bfloat16(f);   // RNE
    return __builtin_bit_cast(unsigned short, h);
}

__device__ __forceinline__ float bf2f(unsigned short u) {
    return __bfloat162float(__builtin_bit_cast(__hip_bfloat16, u));
}

// unpack a dword holding 2 bf16 (lo,hi) into 2 fp32 — 2 VALU ops
__device__ __forceinline__ void unpack2(unsigned int u, float& lo, float& hi) {
    lo = __builtin_bit_cast(float, u << 16);
    hi = __builtin_bit_cast(float, u & 0xFFFF0000u);
}

__device__ __forceinline__ void unpack8(uint4 u, float* f) {
    unpack2(u.x, f[0], f[1]);
    unpack2(u.y, f[2], f[3]);
    unpack2(u.z, f[4], f[5]);
    unpack2(u.w, f[6], f[7]);
}

// Build a bf16x8 MFMA fragment from 8 consecutive fp32 (16B-aligned).
// Verified class (R7): 2x float4 reads (LDS or global) + VALU cvt.
__device__ __forceinline__ bf16x8 frag8(const float* p) {
    const float4 x = *reinterpret_cast<const float4*>(p);
    const float4 y = *reinterpret_cast<const float4*>(p + 4);
    us8 u;
    u[0] = f2bf(x.x); u[1] = f2bf(x.y); u[2] = f2bf(x.z); u[3] = f2bf(x.w);
    u[4] = f2bf(y.x); u[5] = f2bf(y.y); u[6] = f2bf(y.z); u[7] = f2bf(y.w);
    return __builtin_bit_cast(bf16x8, u);
}

// async global->LDS, 16B per lane; lds ptr must be wave-uniform base.
__device__ __forceinline__ void gld_lds16(const void* g, void* l) {
    __builtin_amdgcn_global_load_lds(
        (const __attribute__((address_space(1))) void*)g,
        (__attribute__((address_space(3))) void*)l, 16, 0, 0);
}

// ---------------------------------------------------------------------------
// fused converts (R9/R10/R11-verified): blocks [0,1024): x->bf16; rest: W^T
// ---------------------------------------------------------------------------
__global__ __launch_bounds__(256) void convert_kernel(
    const float* __restrict__ x,
    const float* __restrict__ Wq, const float* __restrict__ Wk,
    const float* __restrict__ Wv, const float* __restrict__ Wo,
    unsigned short* __restrict__ xb,
    unsigned short* __restrict__ Wt, unsigned short* __restrict__ Wot)
{
    const int tid = threadIdx.x;
    if (blockIdx.x < NTOK * D_MODEL / 8 / 256) {
        const int i = (blockIdx.x * 256 + tid) * 8;
        const float4 a = *reinterpret_cast<const float4*>(&x[i]);
        const float4 b = *reinterpret_cast<const float4*>(&x[i + 4]);
        ushort4 u0 = { f2bf(a.x), f2bf(a.y), f2bf(a.z), f2bf(a.w) };
        ushort4 u1 = { f2bf(b.x), f2bf(b.y), f2bf(b.z), f2bf(b.w) };
        *reinterpret_cast<ushort4*>(&xb[i]) = u0;
        *reinterpret_cast<ushort4*>(&xb[i + 4]) = u1;
        return;
    }
    __shared__ float Ls[64][65];
    const int bid = blockIdx.x - NTOK * D_MODEL / 8 / 256;
    const int wi = bid >> 4;
    const int ti = bid & 15;
    const int k0 = (ti >> 2) * 64, n0 = (ti & 3) * 64;
    const float* W = wi == 0 ? Wq : wi == 1 ? Wk : wi == 2 ? Wv : Wo;
#pragma unroll
    for (int i = 0; i < 16; ++i) {
        const int idx = i * 256 + tid;
        const int r = idx >> 6, c = idx & 63;
        Ls[r][c] = W[(size_t)(k0 + r) * D_MODEL + n0 + c];
    }
    __syncthreads();
    unsigned short* outp = (wi < 3) ? (Wt + (size_t)(wi * 256 + n0) * D_MODEL + k0)
                                    : (Wot + (size_t)n0 * D_MODEL + k0);
#pragma unroll
    for (int i = 0; i < 16; ++i) {
        const int idx = i * 256 + tid;
        const int rn = idx >> 6, ck = idx & 63;
        outp[(size_t)rn * D_MODEL + ck] = f2bf(Ls[ck][rn]);
    }
}

// ---------------------------------------------------------------------------
// MFMA bf16 GEMM — 64x64 tile variant for high occupancy on skinny shapes.
// BK=64, global_load_lds(16B), chunk-XOR swizzle (identical op classes &
// lane->fragment mapping to the verified 128x128 kernel; geometry only).
// Each of 4 waves: 16 m-rows x 64 n-cols (4 n-tiles of 16x16).
// MODE 0: qkv, grid = 128 mtiles * 12 ntiles; elu1 on Q,K; bf16 out.
// MODE 1: ogemm, grid = 128 mtiles * 4 ntiles; fp32 out.
// ---------------------------------------------------------------------------
template<int MODE>
__global__ __launch_bounds__(256) void mfma_gemm_kernel(
    const unsigned short* __restrict__ A,
    const unsigned short* __restrict__ Bt,
    const float* __restrict__ b0, const float* __restrict__ b1,
    const float* __restrict__ b2,
    void* __restrict__ O0, void* __restrict__ O1, void* __restrict__ O2)
{
    __shared__ __align__(16) unsigned short As[64 * 64];
    __shared__ __align__(16) unsigned short Bs[64 * 64];
    const int tid = threadIdx.x;
    const int wave = tid >> 6, lane = tid & 63;
    const int la = lane & 15, q = lane >> 4;

    int mtile, ntile;
    if (MODE == 0) { ntile = blockIdx.x % 12; mtile = blockIdx.x / 12; }
    else           { ntile = blockIdx.x & 3;  mtile = blockIdx.x >> 2; }
    const int m0 = mtile * 64, n0 = ntile * 64;

    const unsigned short* Ab = A  + (size_t)m0 * D_MODEL;
    const unsigned short* Bb = Bt + (size_t)n0 * D_MODEL;

    f32x4 acc[4];
#pragma unroll
    for (int i = 0; i < 4; ++i) acc[i] = (f32x4){0.f, 0.f, 0.f, 0.f};

    for (int k0 = 0; k0 < D_MODEL; k0 += 64) {
        // stage 64 rows x 64 k (8 chunks of 16B): 512 chunks per matrix
#pragma unroll
        for (int i = 0; i < 2; ++i) {
            const int bslot = i * 256 + wave * 64;   // wave-uniform base
            const int slot = bslot + lane;
            const int m = slot >> 3, s = slot & 7;
            const int g = s ^ (m & 7);
            gld_lds16(Ab + (size_t)m * D_MODEL + k0 + g * 8, &As[bslot * 8]);
            gld_lds16(Bb + (size_t)m * D_MODEL + k0 + g * 8, &Bs[bslot * 8]);
        }
        __syncthreads();

        bf16x8 af[2], bfr[4][2];
#pragma unroll
        for (int kh = 0; kh < 2; ++kh) {
            const int g = kh * 4 + q;
            const int m = wave * 16 + la;
            af[kh] = *reinterpret_cast<const bf16x8*>(
                &As[m * 64 + ((g ^ (m & 7)) << 3)]);
#pragma unroll
            for (int ni = 0; ni < 4; ++ni) {
                const int n = ni * 16 + la;
                bfr[ni][kh] = *reinterpret_cast<const bf16x8*>(
                    &Bs[n * 64 + ((g ^ (n & 7)) << 3)]);
            }
        }
#pragma unroll
        for (int ni = 0; ni < 4; ++ni) {
            acc[ni] = __builtin_amdgcn_mfma_f32_16x16x32_bf16(
                af[0], bfr[ni][0], acc[ni], 0, 0, 0);
            acc[ni] = __builtin_amdgcn_mfma_f32_16x16x32_bf16(
                af[1], bfr[ni][1], acc[ni], 0, 0, 0);
        }
        __syncthreads();
    }

    // C/D layout: col=lane&15, row=(lane>>4)*4+reg
#pragma unroll
    for (int ni = 0; ni < 4; ++ni) {
        const int row = m0 + wave * 16 + q * 4;
        const int col = n0 + ni * 16 + la;
        if (MODE == 0) {
            const int which = col >> 8;          // block-uniform
            const int cl = col & 255;
            unsigned short* Out = (unsigned short*)
                (which == 0 ? O0 : which == 1 ? O1 : O2);
            const float* bias = which == 0 ? b0 : which == 1 ? b1 : b2;
            const int act = (which < 2);
            const float bv = bias[cl];
#pragma unroll
            for (int r = 0; r < 4; ++r) {
                float v = acc[ni][r] + bv;
                if (act) v = elu1(v);
                Out[(size_t)(row + r) * D_MODEL + cl] = f2bf(v);
            }
        } else {
            float* Out = (float*)O0;
            const float bv = b0[col];
#pragma unroll
            for (int r = 0; r < 4; ++r)
                Out[(size_t)(row + r) * D_MODEL + col] = acc[ni][r] + bv;
        }
    }
}

// ---------------------------------------------------------------------------
// chunksum (R10/R11-verified): Pt_c[m][d] = sum_t V[t][m] K[t][d]; Z_c[d].
// ---------------------------------------------------------------------------
__global__ __launch_bounds__(256) void chunksum_kernel(
    const unsigned short* __restrict__ Kb, const unsigned short* __restrict__ Vb,
    float* __restrict__ Pt, float* __restrict__ Zc)
{
    __shared__ __align__(16) float Ktf[DHEAD * LSTRF];   // Ktf[d][t]
    __shared__ __align__(16) float Vtf[DHEAD * LSTRF];   // Vtf[m][t]
    const int tid = threadIdx.x;
    const int c  = blockIdx.x % NCHUNK;
    const int bh = blockIdx.x / NCHUNK;
    const int b = bh / NHEADS, h = bh % NHEADS;
    const size_t gbase = ((size_t)(b * TSEQ + c * CHUNK)) * D_MODEL + h * DHEAD;

#pragma unroll
    for (int i = 0; i < 2; ++i) {
        const int idx = i * 256 + tid;           // 0..511
        const int t = idx >> 3, e0 = (idx & 7) * 8;
        float kf[8], vf[8];
        unpack8(*reinterpret_cast<const uint4*>(&Kb[gbase + (size_t)t * D_MODEL + e0]), kf);
        unpack8(*reinterpret_cast<const uint4*>(&Vb[gbase + (size_t)t * D_MODEL + e0]), vf);
#pragma unroll
        for (int j = 0; j < 8; ++j) {
            Ktf[(e0 + j) * LSTRF + t] = kf[j];
            Vtf[(e0 + j) * LSTRF + t] = vf[j];
        }
    }
    __syncthreads();

    const int wave = tid >> 6, lane = tid & 63;
    const int la = lane & 15, q = lane >> 4;
    const int wm = (wave >> 1) * 32, wn = (wave & 1) * 32;   // m rows, d cols

    f32x4 acc[2][2];
#pragma unroll
    for (int i = 0; i < 2; ++i)
#pragma unroll
        for (int j = 0; j < 2; ++j) acc[i][j] = (f32x4){0.f, 0.f, 0.f, 0.f};

#pragma unroll
    for (int ks = 0; ks < 2; ++ks) {
        const int ko = ks * 32 + q * 8;                       // k = t
        const bf16x8 a0  = frag8(&Vtf[(wm + la) * LSTRF + ko]);
        const bf16x8 a1  = frag8(&Vtf[(wm + 16 + la) * LSTRF + ko]);
        const bf16x8 bb0 = frag8(&Ktf[(wn + la) * LSTRF + ko]);
        const bf16x8 bb1 = frag8(&Ktf[(wn + 16 + la) * LSTRF + ko]);
        acc[0][0] = __builtin_amdgcn_mfma_f32_16x16x32_bf16(a0, bb0, acc[0][0], 0, 0, 0);
        acc[0][1] = __builtin_amdgcn_mfma_f32_16x16x32_bf16(a0, bb1, acc[0][1], 0, 0, 0);
        acc[1][0] = __builtin_amdgcn_mfma_f32_16x16x32_bf16(a1, bb0, acc[1][0], 0, 0, 0);
        acc[1][1] = __builtin_amdgcn_mfma_f32_16x16x32_bf16(a1, bb1, acc[1][1], 0, 0, 0);
    }

    float* Pb = Pt + (size_t)blockIdx.x * (DHEAD * DHEAD);
#pragma unroll
    for (int mi = 0; mi < 2; ++mi)
#pragma unroll
        for (int ni = 0; ni < 2; ++ni) {
            const int row = wm + mi * 16 + q * 4;   // m
            const int col = wn + ni * 16 + la;      // d
#pragma unroll
            for (int r = 0; r < 4; ++r)
                Pb[(row + r) * DHEAD + col] = acc[mi][ni][r];
        }

    if (tid < DHEAD) {
        float z = 0.f;
        for (int t = 0; t < CHUNK; ++t) z += Ktf[tid * LSTRF + t];
        Zc[(size_t)blockIdx.x * DHEAD + tid] = z;
    }
}

// ---------------------------------------------------------------------------
// prefix (R7/R11-verified): exclusive scan over chunks, register-buffered.
// ---------------------------------------------------------------------------
__global__ __launch_bounds__(256) void prefix_kernel(
    float* __restrict__ P, float* __restrict__ Zc)
{
    const int tid = threadIdx.x;
    if (blockIdx.x < NBH * 16) {
        const int bh = blockIdx.x >> 4;
        const int e = ((blockIdx.x & 15) << 8) + tid;
        const size_t base = (size_t)bh * NCHUNK * (DHEAD * DHEAD) + e;
        float v[NCHUNK];
#pragma unroll
        for (int c = 0; c < NCHUNK; ++c) v[c] = P[base + (size_t)c * (DHEAD * DHEAD)];
        float s = 0.f;
#pragma unroll
        for (int c = 0; c < NCHUNK; ++c) {
            const float t = v[c];
            P[base + (size_t)c * (DHEAD * DHEAD)] = s;
            s += t;
        }
    } else {
        const int j = ((int)(blockIdx.x - NBH * 16) << 8) + tid;
        if (j < NBH * DHEAD) {
            const int bh = j >> 6, d = j & 63;
            float v[NCHUNK];
#pragma unroll
            for (int c = 0; c < NCHUNK; ++c) v[c] = Zc[(bh * NCHUNK + c) * DHEAD + d];
            float s = 0.f;
#pragma unroll
            for (int c = 0; c < NCHUNK; ++c) {
                const float t = v[c];
                Zc[(bh * NCHUNK + c) * DHEAD + d] = s;
                s += t;
            }
        }
    }
}

// ---------------------------------------------------------------------------
// chunkout (R11-verified): MFMA compute + uint4 staging; Pt/Zx scanned.
// ---------------------------------------------------------------------------
__global__ __launch_bounds__(256) void chunkout_kernel(
    const unsigned short* __restrict__ Qb, const unsigned short* __restrict__ Kb,
    const unsigned short* __restrict__ Vb,
    const float* __restrict__ Pt, const float* __restrict__ Zx,
    unsigned short* __restrict__ Ob)
{
    __shared__ __align__(16) float Qs[CHUNK * LSTRF];    // Qs[t][d]
    __shared__ __align__(16) float Ks[CHUNK * LSTRF];    // Ks[s][d]
    __shared__ __align__(16) float Vtf[DHEAD * LSTRF];   // Vtf[m][s]
    __shared__ __align__(16) float At[CHUNK * LSTRF];    // At[t][s] masked QK^T
    __shared__ float zsh[DHEAD];
    __shared__ float dnm[CHUNK];

    const int tid = threadIdx.x;
    const int c  = blockIdx.x % NCHUNK;
    const int bh = blockIdx.x / NCHUNK;
    const int b = bh / NHEADS, h = bh % NHEADS;
    const size_t gbase = ((size_t)(b * TSEQ + c * CHUNK)) * D_MODEL + h * DHEAD;
    const float* Pp = Pt + (size_t)blockIdx.x * (DHEAD * DHEAD);

#pragma unroll
    for (int i = 0; i < 2; ++i) {
        const int idx = i * 256 + tid;
        const int t = idx >> 3, e0 = (idx & 7) * 8;
        float qf[8], kf[8], vf[8];
        unpack8(*reinterpret_cast<const uint4*>(&Qb[gbase + (size_t)t * D_MODEL + e0]), qf);
        unpack8(*reinterpret_cast<const uint4*>(&Kb[gbase + (size_t)t * D_MODEL + e0]), kf);
        unpack8(*reinterpret_cast<const uint4*>(&Vb[gbase + (size_t)t * D_MODEL + e0]), vf);
        *reinterpret_cast<float4*>(&Qs[t * LSTRF + e0])     = (float4){qf[0], qf[1], qf[2], qf[3]};
        *reinterpret_cast<float4*>(&Qs[t * LSTRF + e0 + 4]) = (float4){qf[4], qf[5], qf[6], qf[7]};
        *reinterpret_cast<float4*>(&Ks[t * LSTRF + e0])     = (float4){kf[0], kf[1], kf[2], kf[3]};
        *reinterpret_cast<float4*>(&Ks[t * LSTRF + e0 + 4]) = (float4){kf[4], kf[5], kf[6], kf[7]};
#pragma unroll
        for (int j = 0; j < 8; ++j)
            Vtf[(e0 + j) * LSTRF + t] = vf[j];
    }
    if (tid < DHEAD)
        zsh[tid] = Zx[((size_t)bh * NCHUNK + c) * DHEAD + tid];
    __syncthreads();

    const int wave = tid >> 6, lane = tid & 63;
    const int la = lane & 15, q = lane >> 4;
    const int wt = (wave >> 1) * 32, wn = (wave & 1) * 32;

    // phase 1: A = Q K^T
    f32x4 acc[2][2];
#pragma unroll
    for (int i = 0; i < 2; ++i)
#pragma unroll
        for (int j = 0; j < 2; ++j) acc[i][j] = (f32x4){0.f, 0.f, 0.f, 0.f};
#pragma unroll
    for (int ks = 0; ks < 2; ++ks) {
        const int ko = ks * 32 + q * 8;
        const bf16x8 a0  = frag8(&Qs[(wt + la) * LSTRF + ko]);
        const bf16x8 a1  = frag8(&Qs[(wt + 16 + la) * LSTRF + ko]);
        const bf16x8 bb0 = frag8(&Ks[(wn + la) * LSTRF + ko]);
        const bf16x8 bb1 = frag8(&Ks[(wn + 16 + la) * LSTRF + ko]);
        acc[0][0] = __builtin_amdgcn_mfma_f32_16x16x32_bf16(a0, bb0, acc[0][0], 0, 0, 0);
        acc[0][1] = __builtin_amdgcn_mfma_f32_16x16x32_bf16(a0, bb1, acc[0][1], 0, 0, 0);
        acc[1][0] = __builtin_amdgcn_mfma_f32_16x16x32_bf16(a1, bb0, acc[1][0], 0, 0, 0);
        acc[1][1] = __builtin_amdgcn_mfma_f32_16x16x32_bf16(a1, bb1, acc[1][1], 0, 0, 0);
    }
#pragma unroll
    for (int mi = 0; mi < 2; ++mi)
#pragma unroll
        for (int ni = 0; ni < 2; ++ni) {
            const int t0 = wt + mi * 16 + q * 4;
            const int s  = wn + ni * 16 + la;
#pragma unroll
            for (int r = 0; r < 4; ++r)
                At[(t0 + r) * LSTRF + s] = (s <= t0 + r) ? acc[mi][ni][r] : 0.f;
        }
    __syncthreads();

    // phase 2: denom[t] = rowsum(A) + Q . Z_prev + eps
    if (tid < CHUNK) {
        float dv = 0.f;
        for (int s = 0; s < CHUNK; ++s) dv += At[tid * LSTRF + s];
        for (int d = 0; d < DHEAD; ++d) dv = fmaf(Qs[tid * LSTRF + d], zsh[d], dv);
        dnm[tid] = dv + EPSV;
    }
    __syncthreads();

    // phase 3: O = Q @ S_prev + A @ V
    f32x4 o[2][2];
#pragma unroll
    for (int i = 0; i < 2; ++i)
#pragma unroll
        for (int j = 0; j < 2; ++j) o[i][j] = (f32x4){0.f, 0.f, 0.f, 0.f};
#pragma unroll
    for (int ks = 0; ks < 2; ++ks) {
        const int ko = ks * 32 + q * 8;                       // k = d
        const bf16x8 a0  = frag8(&Qs[(wt + la) * LSTRF + ko]);
        const bf16x8 a1  = frag8(&Qs[(wt + 16 + la) * LSTRF + ko]);
        const bf16x8 bb0 = frag8(&Pp[(wn + la) * DHEAD + ko]);        // global
        const bf16x8 bb1 = frag8(&Pp[(wn + 16 + la) * DHEAD + ko]);   // global
        o[0][0] = __builtin_amdgcn_mfma_f32_16x16x32_bf16(a0, bb0, o[0][0], 0, 0, 0);
        o[0][1] = __builtin_amdgcn_mfma_f32_16x16x32_bf16(a0, bb1, o[0][1], 0, 0, 0);
        o[1][0] = __builtin_amdgcn_mfma_f32_16x16x32_bf16(a1, bb0, o[1][0], 0, 0, 0);
        o[1][1] = __builtin_amdgcn_mfma_f32_16x16x32_bf16(a1, bb1, o[1][1], 0, 0, 0);
    }
#pragma unroll
    for (int ks = 0; ks < 2; ++ks) {
        const int ko = ks * 32 + q * 8;                       // k = s
        const bf16x8 a0  = frag8(&At[(wt + la) * LSTRF + ko]);
        const bf16x8 a1  = frag8(&At[(wt + 16 + la) * LSTRF + ko]);
        const bf16x8 bb0 = frag8(&Vtf[(wn + la) * LSTRF + ko]);
        const bf16x8 bb1 = frag8(&Vtf[(wn + 16 + la) * LSTRF + ko]);
        o[0][0] = __builtin_amdgcn_mfma_f32_16x16x32_bf16(a0, bb0, o[0][0], 0, 0, 0);
        o[0][1] = __builtin_amdgcn_mfma_f32_16x16x32_bf16(a0, bb1, o[0][1], 0, 0, 0);
        o[1][0] = __builtin_amdgcn_mfma_f32_16x16x32_bf16(a1, bb0, o[1][0], 0, 0, 0);
        o[1][1] = __builtin_amdgcn_mfma_f32_16x16x32_bf16(a1, bb1, o[1][1], 0, 0, 0);
    }

    // epilogue: divide + bf16 scalar stores (verified class)
#pragma unroll
    for (int mi = 0; mi < 2; ++mi)
#pragma unroll
        for (int ni = 0; ni < 2; ++ni) {
            const int t0 = wt + mi * 16 + q * 4;
            const int m  = wn + ni * 16 + la;
#pragma unroll
            for (int r = 0; r < 4; ++r) {
                const float v = o[mi][ni][r] / dnm[t0 + r];
                Ob[gbase + (size_t)(t0 + r) * D_MODEL + m] = f2bf(v);
            }
        }
}

extern "C" void kernel_launch(void* const* d_in, const int* in_sizes, int n_in,
                              void* d_out, int out_size, void* d_ws, size_t ws_size,
                              hipStream_t stream)
{
    const float* x  = (const float*)d_in[0];
    const float* Wq = (const float*)d_in[1];
    const float* bq = (const float*)d_in[2];
    const float* Wk = (const float*)d_in[3];
    const float* bk = (const float*)d_in[4];
    const float* Wv = (const float*)d_in[5];
    const float* bv = (const float*)d_in[6];
    const float* Wo = (const float*)d_in[7];
    const float* bo = (const float*)d_in[8];
    float* out = (float*)d_out;

    const size_t NE = (size_t)NTOK * D_MODEL;               // 2M elems
    unsigned short* xb  = (unsigned short*)d_ws;            // 2M bf16
    unsigned short* Wt  = xb + NE;                          // 768*256
    unsigned short* Wot = Wt + 768 * 256;                   // 256*256
    unsigned short* Qb  = Wot + 256 * 256;                  // 2M
    unsigned short* Kb  = Qb + NE;                          // 2M
    unsigned short* Vb  = Kb + NE;                          // 2M
    unsigned short* Ob  = Vb + NE;                          // 2M
    float* P = (float*)(Ob + NE);                           // 16*32*4096 f32 (8MB)
    float* Z = P + (size_t)NBH * NCHUNK * DHEAD * DHEAD;    // 16*32*64 f32

    convert_kernel<<<NTOK * D_MODEL / 8 / 256 + 64, 256, 0, stream>>>(
        x, Wq, Wk, Wv, Wo, xb, Wt, Wot);
    mfma_gemm_kernel<0><<<(NTOK / 64) * 12, 256, 0, stream>>>(
        xb, Wt, bq, bk, bv, Qb, Kb, Vb);
    chunksum_kernel<<<NBH * NCHUNK, 256, 0, stream>>>(Kb, Vb, P, Z);
    prefix_kernel<<<NBH * 16 + 4, 256, 0, stream>>>(P, Z);
    chunkout_kernel<<<NBH * NCHUNK, 256, 0, stream>>>(Qb, Kb, Vb, P, Z, Ob);
    mfma_gemm_kernel<1><<<(NTOK / 64) * 4, 256, 0, stream>>>(
        Ob, Wot, bo, nullptr, nullptr, out, nullptr, nullptr);
}